// Round 14
// baseline (186.027 us; speedup 1.0000x reference)
//
#include <hip/hip_runtime.h>

#define Bb 2
#define Nn 256
#define Dd 128
#define Rr 32

typedef unsigned short u16;
typedef unsigned int   u32;
typedef __attribute__((ext_vector_type(8))) short bf16x8;
typedef __attribute__((ext_vector_type(4))) float f32x4;
typedef __attribute__((ext_vector_type(2))) u32   u32x2;
typedef __attribute__((ext_vector_type(4))) u32   u32x4;

// one-time bf16-transposed radial weights (fragment-order), filled by prep_kernel
__device__ u16 g_w1t[4*Dd*Rr];   // per p: W1T[dd*32 + kk] = bf16(W1[kk][dd])
__device__ u16 g_w2t[4*Dd*Dd];   // per p: W2T[dd*128 + kk] = bf16(W2[kk][dd])

__device__ __forceinline__ short f2bfs(float f){
  u32 u = __float_as_uint(f);
  u += 0x7FFFu + ((u >> 16) & 1u);   // RNE
  return (short)(u >> 16);
}
__device__ __forceinline__ u16 f2bf(float f){
  u32 u = __float_as_uint(f);
  u += 0x7FFFu + ((u >> 16) & 1u);
  return (u16)(u >> 16);
}
// packed f32x2 -> bf16x2 (RNE), one VALU op
__device__ __forceinline__ u32 cvtpk(float a, float b){
  u32 r;
  asm("v_cvt_pk_bf16_f32 %0, %1, %2" : "=v"(r) : "v"(a), "v"(b));
  return r;
}

// ---- prep: blocks [0,512): h = node_s @ src_w, stored TRANSPOSED h_T[b][d][i]
//      blocks [512,544): weight bf16-transpose
__global__ __launch_bounds__(128) void prep_kernel(
    const float* __restrict__ node_s, const float* __restrict__ src_w,
    const float* __restrict__ r0w1, const float* __restrict__ r1w1,
    const float* __restrict__ r2w1, const float* __restrict__ r3w1,
    const float* __restrict__ r0w2, const float* __restrict__ r1w2,
    const float* __restrict__ r2w2, const float* __restrict__ r3w2,
    float* __restrict__ h_out)
{
  const int bx = blockIdx.x;
  const int t  = threadIdx.x;
  if (bx < Bb*Nn){
    __shared__ float s_row[Dd];
    s_row[t] = node_s[(size_t)bx*Dd + t];
    __syncthreads();
    float acc = 0.f;
    #pragma unroll 8
    for (int k=0;k<Dd;k++) acc += s_row[k]*src_w[k*Dd + t];
    const int b = bx >> 8, i = bx & 255;
    h_out[(size_t)(b*Dd + t)*Nn + i] = acc;       // transposed: [b][d][i]
  } else {
    const int kb = bx - Bb*Nn;          // 0..31
    const int p  = kb >> 3, sl = kb & 7;
    const float* W1 = (p==0)?r0w1:(p==1)?r1w1:(p==2)?r2w1:r3w1;
    const float* W2 = (p==0)?r0w2:(p==1)?r1w2:(p==2)?r2w2:r3w2;
    u16* W1T = g_w1t + p*Dd*Rr;
    u16* W2T = g_w2t + p*Dd*Dd;
    // coalesced reads (linear in), scattered writes (stores don't stall)
    #pragma unroll
    for (int it=0; it<4; it++){
      int in = sl*512 + it*128 + t;                  // in = kk*Dd + dd
      W1T[(in & 127)*Rr + (in >> 7)] = f2bf(W1[in]);
    }
    #pragma unroll
    for (int it=0; it<16; it++){
      int in = sl*2048 + it*128 + t;                 // in = kk*Dd + dd
      W2T[(in & 127)*Dd + (in >> 7)] = f2bf(W2[in]);
    }
  }
}

// ---- main: 8 waves/block, 512 thr, (512,4). Pipelined pair-loop (r13).
// GEMM1: wave w owns hidden cols kk in [w*16,+16), all j (unchanged).
// GEMM2 (r14): WAVE-PAIR split — pair pw=w>>1 owns d in [pw*32,+32); wave
// half=w&1 handles only j-group `half` (32 of 64 j) but BOTH 16-d halves.
// The af A-fragments depend only on (half,mm,ks) -> loaded once per mm and
// reused for nt=0,1: per-wave af reads drop 16->8 ds_read_b128 per chunk
// (r13 had ALL EIGHT waves reading the identical 64x128 tile = 8x LDS
// amplification, ~46% of CU cycles on the LDS pipe). accred covers only the
// wave's j-half -> cross-pair merge via s_red at the end (r5's verified
// pattern). Static base+immediate LDS addressing, odd stride 130, zero-row
// mask, pair-loop scope (no spill) all retained.
__global__ __launch_bounds__(512,4) void se3_mfma18(
    const float* __restrict__ node_v,
    const float* __restrict__ rbf,
    const float* __restrict__ r_hat,
    const float* __restrict__ maskp,
    const float* __restrict__ r0b1, const float* __restrict__ r0b2,
    const float* __restrict__ r1b1, const float* __restrict__ r1b2,
    const float* __restrict__ r2b1, const float* __restrict__ r2b2,
    const float* __restrict__ r3b1, const float* __restrict__ r3b2,
    const float* __restrict__ ln_g, const float* __restrict__ ln_b,
    const float* __restrict__ out_w, const float* __restrict__ out_b,
    const float* __restrict__ v_scale, const float* __restrict__ t_scale,
    const float* __restrict__ h_ws,
    float* __restrict__ out_s, float* __restrict__ out_v, float* __restrict__ out_t)
{
  __shared__ u16   s_rbf[Nn*40];       // 20480: rbf bf16, row stride 40
  __shared__ u16   s_hid[2*64*130];    // 33280: dbuf, row stride 130 (odd dwords)
  __shared__ u16   s_YT[11*264];       //  5808: rows 0..9 = Y*mask, row 10 = zeros
  __shared__ u16   s_Y1r[3*264];       //  1584
  __shared__ float s_red[16*130];      //  8320: wave-pair partial merge (r5 pattern)
  __shared__ float s_msg[Dd];          //   512
  __shared__ float s_xn[Dd];           //   512
  __shared__ float s_part[4*Dd];       //  2048
  __shared__ float s_mv[2];            //     8  -> total 72552 B (2 blocks/CU)

  const int tid  = threadIdx.x;
  const int bi   = blockIdx.x;            // b*N + i
  const int b    = bi >> 8;
  const int lane = tid & 63;
  const int w    = tid >> 6;              // wave 0..7
  const int q    = lane >> 4;
  const int cc   = lane & 15;
  const int hi5  = cc >> 2, lo2 = cc & 3;
  const int dwb  = w*16;                  // GEMM1: this wave's 16 hidden cols
  const int pwb  = (w>>1)*32;             // GEMM2: this pair's 32-d base
  const int half = w & 1;                 // GEMM2: this wave's j-group

  // ---- setup: stacked-Y rows (mask folded), raw Y1, zero row ----
  if (tid < Nn){
    int j = tid;
    size_t pidx = (size_t)bi*Nn + j;
    float mk = maskp[pidx];
    float x = r_hat[pidx*3+0];
    float y = r_hat[pidx*3+1];
    float z = r_hat[pidx*3+2];
    const float SQ3=1.7320508075688772f;
    const float C15=3.8729833462074170f;
    const float C5H=1.1180339887498949f;
    float y1a=SQ3*x, y1b=SQ3*y, y1c=SQ3*z;
    s_YT[0*264+j]=f2bf(mk);
    s_YT[1*264+j]=f2bf(y1a*mk);
    s_YT[2*264+j]=f2bf(y1b*mk);
    s_YT[3*264+j]=f2bf(y1c*mk);
    s_YT[4*264+j]=f2bf(C15*x*y*mk);
    s_YT[5*264+j]=f2bf(C15*y*z*mk);
    s_YT[6*264+j]=f2bf(C5H*(3.f*z*z-1.f)*mk);
    s_YT[7*264+j]=f2bf(C15*x*z*mk);
    s_YT[8*264+j]=f2bf(0.5f*C15*(x*x-y*y)*mk);
    s_YT[9*264+j]=f2bf(mk);
    s_YT[10*264+j]=0;                     // zero row for masked-off lanes
    s_Y1r[0*264+j]=f2bf(y1a);
    s_Y1r[1*264+j]=f2bf(y1b);
    s_Y1r[2*264+j]=f2bf(y1c);
  }

  const float* rbf_blk = rbf + (size_t)bi*Nn*Rr;
  const float* htb     = h_ws + (size_t)b*Dd*Nn;   // h_T[b][d][i]

  // ---- stage rbf as bf16 (row stride 40): packed pairs ----
  for (int idx=tid; idx<Nn*Rr/2; idx+=512){
    int j = idx >> 4, r2 = (idx & 15)*2;
    const float* src = &rbf_blk[j*Rr + r2];
    float v0 = src[0], v1 = src[1];
    *(u32*)&s_rbf[j*40 + r2] = cvtpk(v0, v1);
  }

  // ---- node_v B-fragments for the dot MFMA (pair's 32 d-cols, 2 halves) ----
  bf16x8 vBf[2];
  {
    const float* nv = node_v + (size_t)bi*3*Dd;
    #pragma unroll
    for (int nt=0;nt<2;nt++){
      int dd = pwb + nt*16 + cc;
      bf16x8 t = {0,0,0,0,0,0,0,0};
      if (q==0){
        t[0]=f2bfs(nv[0*Dd+dd]);
        t[1]=f2bfs(nv[1*Dd+dd]);
        t[2]=f2bfs(nv[2*Dd+dd]);
      }
      vBf[nt]=t;
    }
  }

  // ---- per-lane LDS u16-index bases (accesses = base + chunk base + imm) ----
  const int rbf_base = cc*40 + q*8;                 // + ch*2560 + jt*640
  const int hw_base  = cc*130 + w*16 + q*4;         // + buf*8320 + jt*2080
  const int af_base  = (half*32 + hi5*8 + lo2)*130 + q*8;  // + buf*8320 + mm*520 + ks*32

  __syncthreads();                       // setup + staging visible

  const f32x4 zf = {0.f,0.f,0.f,0.f};
  f32x4 accred[2] = {zf, zf};            // [nt]; this wave's j-half partial

  // pipeline registers
  bf16x8 w1f;  f32x4 b1v4;               // GEMM1 weights of the pending chunk's p
  bf16x8 w2f[2][4]; float b2v[2];
  const u16* ytq;                        // per-p Y row base (+q*8 folded)

  // rb = u16-index base of the chunk in s_rbf (= ch*2560); bufn in {0,1}
  auto do_gemm1 = [&](int rb, int bufn){
    #pragma unroll
    for (int jt=0;jt<4;jt++){
      bf16x8 rbff = *(const bf16x8*)&s_rbf[rbf_base + rb + jt*640];
      f32x4 hc = __builtin_amdgcn_mfma_f32_16x16x32_bf16(w1f, rbff, zf, 0,0,0);
      float s0,s1,s2,s3;
      {
        float x0=hc[0]+b1v4[0], x1=hc[1]+b1v4[1], x2=hc[2]+b1v4[2], x3=hc[3]+b1v4[3];
        s0 = x0*__builtin_amdgcn_rcpf(1.f+__expf(-x0));
        s1 = x1*__builtin_amdgcn_rcpf(1.f+__expf(-x1));
        s2 = x2*__builtin_amdgcn_rcpf(1.f+__expf(-x2));
        s3 = x3*__builtin_amdgcn_rcpf(1.f+__expf(-x3));
      }
      u32x2 pk = { cvtpk(s0, s1), cvtpk(s2, s3) };
      *(u32x2*)&s_hid[bufn*8320 + hw_base + jt*2080] = pk;
    }
  };

  // choff = ch*64 (j units); bufx in {0,1}
  auto do_gemm2 = [&](int choff, int bufx, int p){
    u32 bB[2][4];                        // [nt][k-slot pair]
    #pragma unroll
    for (int mm=0;mm<2;mm++){
      // af depends only on (half, mm, ks): loaded ONCE, reused for both nt
      bf16x8 af[4];
      #pragma unroll
      for (int ks=0;ks<4;ks++)
        af[ks] = *(const bf16x8*)&s_hid[bufx*8320 + af_base + mm*520 + ks*32];

      // h for both nt of this mm (issued early; MFMA chain covers latency)
      f32x4 hq[2];
      if (p<3){
        #pragma unroll
        for (int nt=0;nt<2;nt++)
          hq[nt] = *(const f32x4*)&htb[(size_t)(pwb+nt*16+cc)*Nn + choff + half*32 + q*8 + mm*4];
      }

      f32x4 dotC[2];
      if (p==3){                         // dot(v, Y1): A rows follow the tile perm
        bf16x8 aY = {0,0,0,0,0,0,0,0};
        if (q==0){
          int jg = choff + half*32 + hi5*8 + mm*4 + lo2;
          aY[0]=(short)s_Y1r[0*264+jg];
          aY[1]=(short)s_Y1r[1*264+jg];
          aY[2]=(short)s_Y1r[2*264+jg];
        }
        #pragma unroll
        for (int nt=0;nt<2;nt++)
          dotC[nt] = __builtin_amdgcn_mfma_f32_16x16x32_bf16(aY, vBf[nt], zf, 0,0,0);
      }

      #pragma unroll
      for (int nt=0;nt<2;nt++){
        f32x4 c2 = zf;
        #pragma unroll
        for (int ks=0;ks<4;ks++)
          c2 = __builtin_amdgcn_mfma_f32_16x16x32_bf16(af[ks], w2f[nt][ks], c2, 0,0,0);
        float g0,g1,g2,g3;
        if (p<3){
          g0=(c2[0]+b2v[nt])*hq[nt][0]; g1=(c2[1]+b2v[nt])*hq[nt][1];
          g2=(c2[2]+b2v[nt])*hq[nt][2]; g3=(c2[3]+b2v[nt])*hq[nt][3];
        } else {
          g0=(c2[0]+b2v[nt])*dotC[nt][0]; g1=(c2[1]+b2v[nt])*dotC[nt][1];
          g2=(c2[2]+b2v[nt])*dotC[nt][2]; g3=(c2[3]+b2v[nt])*dotC[nt][3];
        }
        bB[nt][mm*2+0] = cvtpk(g0, g1);
        bB[nt][mm*2+1] = cvtpk(g2, g3);
      }
    }
    // j-reduction MFMA over this wave's 32-j group (B-frags from registers)
    bf16x8 aR = *(const bf16x8*)(ytq + choff + half*32);
    #pragma unroll
    for (int nt=0;nt<2;nt++){
      u32x4 bw = { bB[nt][0], bB[nt][1], bB[nt][2], bB[nt][3] };
      bf16x8 bG = __builtin_bit_cast(bf16x8, bw);
      accred[nt] = __builtin_amdgcn_mfma_f32_16x16x32_bf16(aR, bG, accred[nt], 0,0,0);
    }
  };

  // prologue: p0 GEMM1 weights + chunk 0 -> buf0
  w1f  = *(const bf16x8*)&g_w1t[(dwb+cc)*Rr + q*8];
  b1v4 = *(const f32x4*)&r0b1[dwb + q*4];
  do_gemm1(0, 0);

  #pragma unroll 1
  for (int p=0;p<4;p++){
    // per-p GEMM2-side state (global reads: before barrier, latency overlaps)
    {
      const u16* W2T = g_w2t + p*Dd*Dd;
      const float* B2p = (p==0)?r0b2:(p==1)?r1b2:(p==2)?r2b2:r3b2;
      #pragma unroll
      for (int nt=0;nt<2;nt++){
        int dd = pwb + nt*16 + cc;
        #pragma unroll
        for (int ks=0;ks<4;ks++)
          w2f[nt][ks] = *(const bf16x8*)&W2T[dd*Dd + ks*32 + q*8];
        b2v[nt] = B2p[dd];
      }
      const int lo = (p==0)?0:(p==1)?1:(p==2)?4:9;
      const int hi = (p==0)?0:(p==1)?3:(p==2)?8:9;
      ytq = &s_YT[((cc>=lo && cc<=hi)?cc:10)*264] + q*8;
    }
    // pair loop: u=0 handles chunks {0,1} (+prefetch ch2), u=1 chunks {2,3}
    // (+prefetch next-p ch0)
    #pragma unroll 1
    for (int u=0; u<2; u++){
      const int rb0   = u*5120;          // s_rbf base of chunk 2u
      const int choff = u*128;           // j-offset of chunk 2u
      __syncthreads();
      do_gemm1(rb0 + 2560, 1);           // ch 2u+1 -> buf1
      do_gemm2(choff, 0, p);             // ch 2u   <- buf0
      __syncthreads();
      if (u==0){
        do_gemm1(rb0 + 5120, 0);         // ch 2 -> buf0
      } else if (p<3){
        w1f  = *(const bf16x8*)&g_w1t[(p+1)*Dd*Rr + (dwb+cc)*Rr + q*8];
        const float* B1n = (p==0)?r1b1:(p==1)?r2b1:r3b1;
        b1v4 = *(const f32x4*)&B1n[dwb + q*4];
        do_gemm1(0, 0);                  // next-p ch0 -> buf0
      }
      do_gemm2(choff + 64, 1, p);        // ch 2u+1 <- buf1
    }
  }

  // ---- cross-pair merge (r5 pattern): half1 stores, half0 adds+scatters ----
  if (half){
    #pragma unroll
    for (int nt=0;nt<2;nt++){
      const int d = pwb + nt*16 + cc;
      #pragma unroll
      for (int r=0;r<4;r++)
        s_red[(q*4+r)*130 + d] = accred[nt][r];
    }
  }
  __syncthreads();
  if (!half){
    #pragma unroll
    for (int nt=0;nt<2;nt++){
      const int d = pwb + nt*16 + cc;
      #pragma unroll
      for (int r=0;r<4;r++){
        const int rw = q*4 + r;
        float val = accred[nt][r] + s_red[rw*130 + d];
        if (rw==0)      s_msg[d] = val;
        else if (rw<=3) out_v[(size_t)bi*3*Dd + (size_t)(rw-1)*Dd + d] = val*v_scale[d];
        else if (rw<=8) out_t[(size_t)bi*5*Dd + (size_t)(rw-4)*Dd + d] = val*t_scale[d];
        else if (rw==9) s_xn[d] = val;
      }
    }
  }
  __syncthreads();

  // ---- LayerNorm stats (wave 0) ----
  if (tid < 64){
    float a0=s_msg[tid]+s_xn[tid], a1=s_msg[tid+64]+s_xn[tid+64];
    float s1=a0+a1, s2=a0*a0+a1*a1;
    #pragma unroll
    for (int off=1;off<64;off<<=1){
      s1 += __shfl_xor(s1,off);
      s2 += __shfl_xor(s2,off);
    }
    if (tid==0){
      float m   = s1*(1.f/Dd);
      float var = fmaxf(s2*(1.f/Dd) - m*m, 0.f);
      s_mv[0]=m;
      s_mv[1]=rsqrtf(var+1e-5f);
    }
  }
  __syncthreads();
  if (tid < Dd){
    float msg = s_msg[tid]+s_xn[tid];
    s_xn[tid] = (msg - s_mv[0])*s_mv[1]*ln_g[tid] + ln_b[tid];
  }
  __syncthreads();

  // ---- delta_s = xn @ out_w + out_b (4 k-segments across 512 threads) ----
  {
    int dp = tid & 127, seg = tid >> 7;
    float pa = 0.f;
    #pragma unroll 8
    for (int k=seg*32;k<seg*32+32;k++)
      pa += s_xn[k]*out_w[k*Dd+dp];
    s_part[seg*Dd+dp]=pa;
  }
  __syncthreads();
  if (tid < Dd)
    out_s[(size_t)bi*Dd+tid] = s_part[tid]+s_part[Dd+tid]+s_part[2*Dd+tid]+s_part[3*Dd+tid]+out_b[tid];
}

extern "C" void kernel_launch(void* const* d_in, const int* in_sizes, int n_in,
                              void* d_out, int out_size, void* d_ws, size_t ws_size,
                              hipStream_t stream) {
  const float* node_s = (const float*)d_in[0];
  const float* node_v = (const float*)d_in[1];
  // d_in[2] = node_t (unused by reference)
  const float* rbf    = (const float*)d_in[3];
  const float* r_hat  = (const float*)d_in[4];
  const float* maskp  = (const float*)d_in[5];
  const float* r0w1=(const float*)d_in[6],  *r0b1=(const float*)d_in[7];
  const float* r0w2=(const float*)d_in[8],  *r0b2=(const float*)d_in[9];
  const float* r1w1=(const float*)d_in[10], *r1b1=(const float*)d_in[11];
  const float* r1w2=(const float*)d_in[12], *r1b2=(const float*)d_in[13];
  const float* r2w1=(const float*)d_in[14], *r2b1=(const float*)d_in[15];
  const float* r2w2=(const float*)d_in[16], *r2b2=(const float*)d_in[17];
  const float* r3w1=(const float*)d_in[18], *r3b1=(const float*)d_in[19];
  const float* r3w2=(const float*)d_in[20], *r3b2=(const float*)d_in[21];
  const float* src_w  =(const float*)d_in[22];
  const float* ln_g   =(const float*)d_in[23];
  const float* ln_b   =(const float*)d_in[24];
  const float* out_w  =(const float*)d_in[25];
  const float* out_b  =(const float*)d_in[26];
  const float* v_scale=(const float*)d_in[27];
  const float* t_scale=(const float*)d_in[28];

  float* h_ws = (float*)d_ws;                    // h_T: 2*128*256 f32 = 256 KiB
  float* out_s = (float*)d_out;
  float* out_v = out_s + (size_t)Bb*Nn*Dd;
  float* out_t = out_v + (size_t)Bb*Nn*3*Dd;

  prep_kernel<<<dim3(Bb*Nn + 32), dim3(128), 0, stream>>>(
      node_s, src_w,
      r0w1, r1w1, r2w1, r3w1, r0w2, r1w2, r2w2, r3w2,
      h_ws);
  se3_mfma18<<<dim3(Bb*Nn), dim3(512), 0, stream>>>(
      node_v, rbf, r_hat, maskp,
      r0b1,r0b2, r1b1,r1b2, r2b1,r2b2, r3b1,r3b2,
      ln_g, ln_b, out_w, out_b, v_scale, t_scale,
      h_ws, out_s, out_v, out_t);
}

// Round 15
// 184.365 us; speedup vs baseline: 1.0090x; 1.0090x over previous
//
#include <hip/hip_runtime.h>

#define Bb 2
#define Nn 256
#define Dd 128
#define Rr 32

typedef unsigned short u16;
typedef unsigned int   u32;
typedef __attribute__((ext_vector_type(8))) short bf16x8;
typedef __attribute__((ext_vector_type(4))) float f32x4;
typedef __attribute__((ext_vector_type(2))) u32   u32x2;
typedef __attribute__((ext_vector_type(4))) u32   u32x4;

// one-time bf16-transposed radial weights (fragment-order), filled by prep_kernel
__device__ u16 g_w1t[4*Dd*Rr];   // per p: W1T[dd*32 + kk] = bf16(W1[kk][dd])
__device__ u16 g_w2t[4*Dd*Dd];   // per p: W2T[dd*128 + kk] = bf16(W2[kk][dd])

__device__ __forceinline__ short f2bfs(float f){
  u32 u = __float_as_uint(f);
  u += 0x7FFFu + ((u >> 16) & 1u);   // RNE
  return (short)(u >> 16);
}
__device__ __forceinline__ u16 f2bf(float f){
  u32 u = __float_as_uint(f);
  u += 0x7FFFu + ((u >> 16) & 1u);
  return (u16)(u >> 16);
}
// packed f32x2 -> bf16x2 (RNE), one VALU op
__device__ __forceinline__ u32 cvtpk(float a, float b){
  u32 r;
  asm("v_cvt_pk_bf16_f32 %0, %1, %2" : "=v"(r) : "v"(a), "v"(b));
  return r;
}

// ---- prep: blocks [0,512): h = node_s @ src_w, stored TRANSPOSED h_T[b][d][i]
//      blocks [512,544): weight bf16-transpose
__global__ __launch_bounds__(128) void prep_kernel(
    const float* __restrict__ node_s, const float* __restrict__ src_w,
    const float* __restrict__ r0w1, const float* __restrict__ r1w1,
    const float* __restrict__ r2w1, const float* __restrict__ r3w1,
    const float* __restrict__ r0w2, const float* __restrict__ r1w2,
    const float* __restrict__ r2w2, const float* __restrict__ r3w2,
    float* __restrict__ h_out)
{
  const int bx = blockIdx.x;
  const int t  = threadIdx.x;
  if (bx < Bb*Nn){
    __shared__ float s_row[Dd];
    s_row[t] = node_s[(size_t)bx*Dd + t];
    __syncthreads();
    float acc = 0.f;
    #pragma unroll 8
    for (int k=0;k<Dd;k++) acc += s_row[k]*src_w[k*Dd + t];
    const int b = bx >> 8, i = bx & 255;
    h_out[(size_t)(b*Dd + t)*Nn + i] = acc;       // transposed: [b][d][i]
  } else {
    const int kb = bx - Bb*Nn;          // 0..31
    const int p  = kb >> 3, sl = kb & 7;
    const float* W1 = (p==0)?r0w1:(p==1)?r1w1:(p==2)?r2w1:r3w1;
    const float* W2 = (p==0)?r0w2:(p==1)?r1w2:(p==2)?r2w2:r3w2;
    u16* W1T = g_w1t + p*Dd*Rr;
    u16* W2T = g_w2t + p*Dd*Dd;
    // coalesced reads (linear in), scattered writes (stores don't stall)
    #pragma unroll
    for (int it=0; it<4; it++){
      int in = sl*512 + it*128 + t;                  // in = kk*Dd + dd
      W1T[(in & 127)*Rr + (in >> 7)] = f2bf(W1[in]);
    }
    #pragma unroll
    for (int it=0; it<16; it++){
      int in = sl*2048 + it*128 + t;                 // in = kk*Dd + dd
      W2T[(in & 127)*Dd + (in >> 7)] = f2bf(W2[in]);
    }
  }
}

// ---- main: 8 waves/block, 512 thr, (512,4). Pipelined pair-loop (r13).
// GEMM1: wave w owns hidden cols kk in [w*16,+16), all j.
// GEMM2: wave-pair split (r14) — pair pw=w>>1 owns d in [pw*32,+32); wave
// half=w&1 handles j-group `half` only, both 16-d halves; af A-fragments
// loaded ONCE per mm and reused for nt=0,1 (halves the 8x LDS amplification
// r13 measured at ~44% of CU cycles). accred is j-half partial -> cross-pair
// s_red merge at end. r15 REGISTER DIET (r14 spilled 8.4MB at the 128-reg
// (512,4) budget): (a) p==3 split into a TAIL loop -- main loop p=0..2 has
// only the h-path (no vBf/dotC/aY in its live set), tail has only the
// dot-path; (b) hq loaded per-nt (4 regs) not per-mm (8). Peak live ~110.
__global__ __launch_bounds__(512,4) void se3_mfma19(
    const float* __restrict__ node_v,
    const float* __restrict__ rbf,
    const float* __restrict__ r_hat,
    const float* __restrict__ maskp,
    const float* __restrict__ r0b1, const float* __restrict__ r0b2,
    const float* __restrict__ r1b1, const float* __restrict__ r1b2,
    const float* __restrict__ r2b1, const float* __restrict__ r2b2,
    const float* __restrict__ r3b1, const float* __restrict__ r3b2,
    const float* __restrict__ ln_g, const float* __restrict__ ln_b,
    const float* __restrict__ out_w, const float* __restrict__ out_b,
    const float* __restrict__ v_scale, const float* __restrict__ t_scale,
    const float* __restrict__ h_ws,
    float* __restrict__ out_s, float* __restrict__ out_v, float* __restrict__ out_t)
{
  __shared__ u16   s_rbf[Nn*40];       // 20480: rbf bf16, row stride 40
  __shared__ u16   s_hid[2*64*130];    // 33280: dbuf, row stride 130 (odd dwords)
  __shared__ u16   s_YT[11*264];       //  5808: rows 0..9 = Y*mask, row 10 = zeros
  __shared__ u16   s_Y1r[3*264];       //  1584
  __shared__ float s_red[16*130];      //  8320: wave-pair partial merge
  __shared__ float s_msg[Dd];          //   512
  __shared__ float s_xn[Dd];           //   512
  __shared__ float s_part[4*Dd];       //  2048
  __shared__ float s_mv[2];            //     8  -> total 72552 B (2 blocks/CU)

  const int tid  = threadIdx.x;
  const int bi   = blockIdx.x;            // b*N + i
  const int b    = bi >> 8;
  const int lane = tid & 63;
  const int w    = tid >> 6;              // wave 0..7
  const int q    = lane >> 4;
  const int cc   = lane & 15;
  const int hi5  = cc >> 2, lo2 = cc & 3;
  const int dwb  = w*16;                  // GEMM1: this wave's 16 hidden cols
  const int pwb  = (w>>1)*32;             // GEMM2: this pair's 32-d base
  const int half = w & 1;                 // GEMM2: this wave's j-group

  // ---- setup: stacked-Y rows (mask folded), raw Y1, zero row ----
  if (tid < Nn){
    int j = tid;
    size_t pidx = (size_t)bi*Nn + j;
    float mk = maskp[pidx];
    float x = r_hat[pidx*3+0];
    float y = r_hat[pidx*3+1];
    float z = r_hat[pidx*3+2];
    const float SQ3=1.7320508075688772f;
    const float C15=3.8729833462074170f;
    const float C5H=1.1180339887498949f;
    float y1a=SQ3*x, y1b=SQ3*y, y1c=SQ3*z;
    s_YT[0*264+j]=f2bf(mk);
    s_YT[1*264+j]=f2bf(y1a*mk);
    s_YT[2*264+j]=f2bf(y1b*mk);
    s_YT[3*264+j]=f2bf(y1c*mk);
    s_YT[4*264+j]=f2bf(C15*x*y*mk);
    s_YT[5*264+j]=f2bf(C15*y*z*mk);
    s_YT[6*264+j]=f2bf(C5H*(3.f*z*z-1.f)*mk);
    s_YT[7*264+j]=f2bf(C15*x*z*mk);
    s_YT[8*264+j]=f2bf(0.5f*C15*(x*x-y*y)*mk);
    s_YT[9*264+j]=f2bf(mk);
    s_YT[10*264+j]=0;                     // zero row for masked-off lanes
    s_Y1r[0*264+j]=f2bf(y1a);
    s_Y1r[1*264+j]=f2bf(y1b);
    s_Y1r[2*264+j]=f2bf(y1c);
  }

  const float* rbf_blk = rbf + (size_t)bi*Nn*Rr;
  const float* htb     = h_ws + (size_t)b*Dd*Nn;   // h_T[b][d][i]

  // ---- stage rbf as bf16 (row stride 40): packed pairs ----
  for (int idx=tid; idx<Nn*Rr/2; idx+=512){
    int j = idx >> 4, r2 = (idx & 15)*2;
    const float* src = &rbf_blk[j*Rr + r2];
    float v0 = src[0], v1 = src[1];
    *(u32*)&s_rbf[j*40 + r2] = cvtpk(v0, v1);
  }

  // ---- per-lane LDS u16-index bases (accesses = base + chunk base + imm) ----
  const int rbf_base = cc*40 + q*8;                 // + ch*2560 + jt*640
  const int hw_base  = cc*130 + w*16 + q*4;         // + buf*8320 + jt*2080
  const int af_base  = (half*32 + hi5*8 + lo2)*130 + q*8;  // + buf*8320 + mm*520 + ks*32

  __syncthreads();                       // setup + staging visible

  const f32x4 zf = {0.f,0.f,0.f,0.f};
  f32x4 accred[2] = {zf, zf};            // [nt]; this wave's j-half partial

  // pipeline registers
  bf16x8 w1f;  f32x4 b1v4;               // GEMM1 weights of the pending chunk's p
  bf16x8 w2f[2][4]; float b2v[2];
  const u16* ytq;                        // per-p Y row base (+q*8 folded)

  // rb = u16-index base of the chunk in s_rbf (= ch*2560); bufn in {0,1}
  auto do_gemm1 = [&](int rb, int bufn){
    #pragma unroll
    for (int jt=0;jt<4;jt++){
      bf16x8 rbff = *(const bf16x8*)&s_rbf[rbf_base + rb + jt*640];
      f32x4 hc = __builtin_amdgcn_mfma_f32_16x16x32_bf16(w1f, rbff, zf, 0,0,0);
      float s0,s1,s2,s3;
      {
        float x0=hc[0]+b1v4[0], x1=hc[1]+b1v4[1], x2=hc[2]+b1v4[2], x3=hc[3]+b1v4[3];
        s0 = x0*__builtin_amdgcn_rcpf(1.f+__expf(-x0));
        s1 = x1*__builtin_amdgcn_rcpf(1.f+__expf(-x1));
        s2 = x2*__builtin_amdgcn_rcpf(1.f+__expf(-x2));
        s3 = x3*__builtin_amdgcn_rcpf(1.f+__expf(-x3));
      }
      u32x2 pk = { cvtpk(s0, s1), cvtpk(s2, s3) };
      *(u32x2*)&s_hid[bufn*8320 + hw_base + jt*2080] = pk;
    }
  };

  // GEMM2, h-path only (p<3). choff = ch*64 (j units); bufx in {0,1}
  auto do_gemm2h = [&](int choff, int bufx){
    u32 bB[2][4];                        // [nt][k-slot pair]
    #pragma unroll
    for (int mm=0;mm<2;mm++){
      // af depends only on (half, mm, ks): loaded ONCE, reused for both nt
      bf16x8 af[4];
      #pragma unroll
      for (int ks=0;ks<4;ks++)
        af[ks] = *(const bf16x8*)&s_hid[bufx*8320 + af_base + mm*520 + ks*32];

      #pragma unroll
      for (int nt=0;nt<2;nt++){
        // h for this nt only (4 regs); MFMA chain covers its latency
        f32x4 hq = *(const f32x4*)&htb[(size_t)(pwb+nt*16+cc)*Nn + choff + half*32 + q*8 + mm*4];
        f32x4 c2 = zf;
        #pragma unroll
        for (int ks=0;ks<4;ks++)
          c2 = __builtin_amdgcn_mfma_f32_16x16x32_bf16(af[ks], w2f[nt][ks], c2, 0,0,0);
        float g0=(c2[0]+b2v[nt])*hq[0], g1=(c2[1]+b2v[nt])*hq[1];
        float g2=(c2[2]+b2v[nt])*hq[2], g3=(c2[3]+b2v[nt])*hq[3];
        bB[nt][mm*2+0] = cvtpk(g0, g1);
        bB[nt][mm*2+1] = cvtpk(g2, g3);
      }
    }
    bf16x8 aR = *(const bf16x8*)(ytq + choff + half*32);
    #pragma unroll
    for (int nt=0;nt<2;nt++){
      u32x4 bw = { bB[nt][0], bB[nt][1], bB[nt][2], bB[nt][3] };
      bf16x8 bG = __builtin_bit_cast(bf16x8, bw);
      accred[nt] = __builtin_amdgcn_mfma_f32_16x16x32_bf16(aR, bG, accred[nt], 0,0,0);
    }
  };

  // prologue: p0 GEMM1 weights + chunk 0 -> buf0
  w1f  = *(const bf16x8*)&g_w1t[(dwb+cc)*Rr + q*8];
  b1v4 = *(const f32x4*)&r0b1[dwb + q*4];
  do_gemm1(0, 0);

  // ================= main loop: p = 0,1,2 (h-path only) =================
  #pragma unroll 1
  for (int p=0;p<3;p++){
    {
      const u16* W2T = g_w2t + p*Dd*Dd;
      const float* B2p = (p==0)?r0b2:(p==1)?r1b2:r2b2;
      #pragma unroll
      for (int nt=0;nt<2;nt++){
        int dd = pwb + nt*16 + cc;
        #pragma unroll
        for (int ks=0;ks<4;ks++)
          w2f[nt][ks] = *(const bf16x8*)&W2T[dd*Dd + ks*32 + q*8];
        b2v[nt] = B2p[dd];
      }
      const int lo = (p==0)?0:(p==1)?1:4;
      const int hi = (p==0)?0:(p==1)?3:8;
      ytq = &s_YT[((cc>=lo && cc<=hi)?cc:10)*264] + q*8;
    }
    #pragma unroll 1
    for (int u=0; u<2; u++){
      const int rb0   = u*5120;          // s_rbf base of chunk 2u
      const int choff = u*128;           // j-offset of chunk 2u
      __syncthreads();
      do_gemm1(rb0 + 2560, 1);           // ch 2u+1 -> buf1
      do_gemm2h(choff, 0);               // ch 2u   <- buf0
      __syncthreads();
      if (u==0){
        do_gemm1(rb0 + 5120, 0);         // ch 2 -> buf0
      } else {
        // prefetch next-p GEMM1 weights + ch0 (p+1 <= 3 always here)
        w1f  = *(const bf16x8*)&g_w1t[(p+1)*Dd*Rr + (dwb+cc)*Rr + q*8];
        const float* B1n = (p==0)?r1b1:(p==1)?r2b1:r3b1;
        b1v4 = *(const f32x4*)&B1n[dwb + q*4];
        do_gemm1(0, 0);                  // next-p ch0 -> buf0
      }
      do_gemm2h(choff + 64, 1);          // ch 2u+1 <- buf1
    }
  }

  // ================= tail: p = 3 (dot-path only) =================
  {
    // per-p3 state: w2f, b2v, ytq, and vBf (live ONLY here)
    {
      const u16* W2T = g_w2t + 3*Dd*Dd;
      #pragma unroll
      for (int nt=0;nt<2;nt++){
        int dd = pwb + nt*16 + cc;
        #pragma unroll
        for (int ks=0;ks<4;ks++)
          w2f[nt][ks] = *(const bf16x8*)&W2T[dd*Dd + ks*32 + q*8];
        b2v[nt] = r3b2[dd];
      }
      ytq = &s_YT[((cc==9)?9:10)*264] + q*8;
    }
    bf16x8 vBf[2];
    {
      const float* nv = node_v + (size_t)bi*3*Dd;
      #pragma unroll
      for (int nt=0;nt<2;nt++){
        int dd = pwb + nt*16 + cc;
        bf16x8 t = {0,0,0,0,0,0,0,0};
        if (q==0){
          t[0]=f2bfs(nv[0*Dd+dd]);
          t[1]=f2bfs(nv[1*Dd+dd]);
          t[2]=f2bfs(nv[2*Dd+dd]);
        }
        vBf[nt]=t;
      }
    }

    auto do_gemm2d = [&](int choff, int bufx){
      u32 bB[2][4];
      #pragma unroll
      for (int mm=0;mm<2;mm++){
        bf16x8 af[4];
        #pragma unroll
        for (int ks=0;ks<4;ks++)
          af[ks] = *(const bf16x8*)&s_hid[bufx*8320 + af_base + mm*520 + ks*32];

        bf16x8 aY = {0,0,0,0,0,0,0,0};
        if (q==0){
          int jg = choff + half*32 + hi5*8 + mm*4 + lo2;
          aY[0]=(short)s_Y1r[0*264+jg];
          aY[1]=(short)s_Y1r[1*264+jg];
          aY[2]=(short)s_Y1r[2*264+jg];
        }
        #pragma unroll
        for (int nt=0;nt<2;nt++){
          f32x4 dotC = __builtin_amdgcn_mfma_f32_16x16x32_bf16(aY, vBf[nt], zf, 0,0,0);
          f32x4 c2 = zf;
          #pragma unroll
          for (int ks=0;ks<4;ks++)
            c2 = __builtin_amdgcn_mfma_f32_16x16x32_bf16(af[ks], w2f[nt][ks], c2, 0,0,0);
          float g0=(c2[0]+b2v[nt])*dotC[0], g1=(c2[1]+b2v[nt])*dotC[1];
          float g2=(c2[2]+b2v[nt])*dotC[2], g3=(c2[3]+b2v[nt])*dotC[3];
          bB[nt][mm*2+0] = cvtpk(g0, g1);
          bB[nt][mm*2+1] = cvtpk(g2, g3);
        }
      }
      bf16x8 aR = *(const bf16x8*)(ytq + choff + half*32);
      #pragma unroll
      for (int nt=0;nt<2;nt++){
        u32x4 bw = { bB[nt][0], bB[nt][1], bB[nt][2], bB[nt][3] };
        bf16x8 bG = __builtin_bit_cast(bf16x8, bw);
        accred[nt] = __builtin_amdgcn_mfma_f32_16x16x32_bf16(aR, bG, accred[nt], 0,0,0);
      }
    };

    // buf0 already holds p3-ch0 (staged by main loop's last prefetch)
    #pragma unroll 1
    for (int u=0; u<2; u++){
      const int rb0   = u*5120;
      const int choff = u*128;
      __syncthreads();
      do_gemm1(rb0 + 2560, 1);           // ch 2u+1 -> buf1
      do_gemm2d(choff, 0);               // ch 2u   <- buf0
      __syncthreads();
      if (u==0)
        do_gemm1(rb0 + 5120, 0);         // ch 2 -> buf0
      do_gemm2d(choff + 64, 1);          // ch 2u+1 <- buf1
    }
  }

  // ---- cross-pair merge: half1 stores, half0 adds+scatters ----
  if (half){
    #pragma unroll
    for (int nt=0;nt<2;nt++){
      const int d = pwb + nt*16 + cc;
      #pragma unroll
      for (int r=0;r<4;r++)
        s_red[(q*4+r)*130 + d] = accred[nt][r];
    }
  }
  __syncthreads();
  if (!half){
    #pragma unroll
    for (int nt=0;nt<2;nt++){
      const int d = pwb + nt*16 + cc;
      #pragma unroll
      for (int r=0;r<4;r++){
        const int rw = q*4 + r;
        float val = accred[nt][r] + s_red[rw*130 + d];
        if (rw==0)      s_msg[d] = val;
        else if (rw<=3) out_v[(size_t)bi*3*Dd + (size_t)(rw-1)*Dd + d] = val*v_scale[d];
        else if (rw<=8) out_t[(size_t)bi*5*Dd + (size_t)(rw-4)*Dd + d] = val*t_scale[d];
        else if (rw==9) s_xn[d] = val;
      }
    }
  }
  __syncthreads();

  // ---- LayerNorm stats (wave 0) ----
  if (tid < 64){
    float a0=s_msg[tid]+s_xn[tid], a1=s_msg[tid+64]+s_xn[tid+64];
    float s1=a0+a1, s2=a0*a0+a1*a1;
    #pragma unroll
    for (int off=1;off<64;off<<=1){
      s1 += __shfl_xor(s1,off);
      s2 += __shfl_xor(s2,off);
    }
    if (tid==0){
      float m   = s1*(1.f/Dd);
      float var = fmaxf(s2*(1.f/Dd) - m*m, 0.f);
      s_mv[0]=m;
      s_mv[1]=rsqrtf(var+1e-5f);
    }
  }
  __syncthreads();
  if (tid < Dd){
    float msg = s_msg[tid]+s_xn[tid];
    s_xn[tid] = (msg - s_mv[0])*s_mv[1]*ln_g[tid] + ln_b[tid];
  }
  __syncthreads();

  // ---- delta_s = xn @ out_w + out_b (4 k-segments across 512 threads) ----
  {
    int dp = tid & 127, seg = tid >> 7;
    float pa = 0.f;
    #pragma unroll 8
    for (int k=seg*32;k<seg*32+32;k++)
      pa += s_xn[k]*out_w[k*Dd+dp];
    s_part[seg*Dd+dp]=pa;
  }
  __syncthreads();
  if (tid < Dd)
    out_s[(size_t)bi*Dd+tid] = s_part[tid]+s_part[Dd+tid]+s_part[2*Dd+tid]+s_part[3*Dd+tid]+out_b[tid];
}

extern "C" void kernel_launch(void* const* d_in, const int* in_sizes, int n_in,
                              void* d_out, int out_size, void* d_ws, size_t ws_size,
                              hipStream_t stream) {
  const float* node_s = (const float*)d_in[0];
  const float* node_v = (const float*)d_in[1];
  // d_in[2] = node_t (unused by reference)
  const float* rbf    = (const float*)d_in[3];
  const float* r_hat  = (const float*)d_in[4];
  const float* maskp  = (const float*)d_in[5];
  const float* r0w1=(const float*)d_in[6],  *r0b1=(const float*)d_in[7];
  const float* r0w2=(const float*)d_in[8],  *r0b2=(const float*)d_in[9];
  const float* r1w1=(const float*)d_in[10], *r1b1=(const float*)d_in[11];
  const float* r1w2=(const float*)d_in[12], *r1b2=(const float*)d_in[13];
  const float* r2w1=(const float*)d_in[14], *r2b1=(const float*)d_in[15];
  const float* r2w2=(const float*)d_in[16], *r2b2=(const float*)d_in[17];
  const float* r3w1=(const float*)d_in[18], *r3b1=(const float*)d_in[19];
  const float* r3w2=(const float*)d_in[20], *r3b2=(const float*)d_in[21];
  const float* src_w  =(const float*)d_in[22];
  const float* ln_g   =(const float*)d_in[23];
  const float* ln_b   =(const float*)d_in[24];
  const float* out_w  =(const float*)d_in[25];
  const float* out_b  =(const float*)d_in[26];
  const float* v_scale=(const float*)d_in[27];
  const float* t_scale=(const float*)d_in[28];

  float* h_ws = (float*)d_ws;                    // h_T: 2*128*256 f32 = 256 KiB
  float* out_s = (float*)d_out;
  float* out_v = out_s + (size_t)Bb*Nn*Dd;
  float* out_t = out_v + (size_t)Bb*Nn*3*Dd;

  prep_kernel<<<dim3(Bb*Nn + 32), dim3(128), 0, stream>>>(
      node_s, src_w,
      r0w1, r1w1, r2w1, r3w1, r0w2, r1w2, r2w2, r3w2,
      h_ws);
  se3_mfma19<<<dim3(Bb*Nn), dim3(512), 0, stream>>>(
      node_v, rbf, r_hat, maskp,
      r0b1,r0b2, r1b1,r1b2, r2b1,r2b2, r3b1,r3b2,
      ln_g, ln_b, out_w, out_b, v_scale, t_scale,
      h_ws, out_s, out_v, out_t);
}

// Round 16
// 173.406 us; speedup vs baseline: 1.0728x; 1.0632x over previous
//
#include <hip/hip_runtime.h>

#define Bb 2
#define Nn 256
#define Dd 128
#define Rr 32

typedef unsigned short u16;
typedef unsigned int   u32;
typedef __attribute__((ext_vector_type(8))) short bf16x8;
typedef __attribute__((ext_vector_type(4))) float f32x4;
typedef __attribute__((ext_vector_type(2))) u32   u32x2;
typedef __attribute__((ext_vector_type(4))) u32   u32x4;

// one-time bf16-transposed radial weights (fragment-order), filled by prep_kernel
__device__ u16 g_w1t[4*Dd*Rr];   // per p: W1T[dd*32 + kk] = bf16(W1[kk][dd])
__device__ u16 g_w2t[4*Dd*Dd];   // per p: W2T[dd*128 + kk] = bf16(W2[kk][dd])

__device__ __forceinline__ short f2bfs(float f){
  u32 u = __float_as_uint(f);
  u += 0x7FFFu + ((u >> 16) & 1u);   // RNE
  return (short)(u >> 16);
}
__device__ __forceinline__ u16 f2bf(float f){
  u32 u = __float_as_uint(f);
  u += 0x7FFFu + ((u >> 16) & 1u);
  return (u16)(u >> 16);
}
// packed f32x2 -> bf16x2 (RNE), one VALU op
__device__ __forceinline__ u32 cvtpk(float a, float b){
  u32 r;
  asm("v_cvt_pk_bf16_f32 %0, %1, %2" : "=v"(r) : "v"(a), "v"(b));
  return r;
}

// ---- prep: blocks [0,512): h = node_s @ src_w, stored TRANSPOSED h_T[b][d][i]
//      blocks [512,544): weight bf16-transpose
__global__ __launch_bounds__(128) void prep_kernel(
    const float* __restrict__ node_s, const float* __restrict__ src_w,
    const float* __restrict__ r0w1, const float* __restrict__ r1w1,
    const float* __restrict__ r2w1, const float* __restrict__ r3w1,
    const float* __restrict__ r0w2, const float* __restrict__ r1w2,
    const float* __restrict__ r2w2, const float* __restrict__ r3w2,
    float* __restrict__ h_out)
{
  const int bx = blockIdx.x;
  const int t  = threadIdx.x;
  if (bx < Bb*Nn){
    __shared__ float s_row[Dd];
    s_row[t] = node_s[(size_t)bx*Dd + t];
    __syncthreads();
    float acc = 0.f;
    #pragma unroll 8
    for (int k=0;k<Dd;k++) acc += s_row[k]*src_w[k*Dd + t];
    const int b = bx >> 8, i = bx & 255;
    h_out[(size_t)(b*Dd + t)*Nn + i] = acc;       // transposed: [b][d][i]
  } else {
    const int kb = bx - Bb*Nn;          // 0..31
    const int p  = kb >> 3, sl = kb & 7;
    const float* W1 = (p==0)?r0w1:(p==1)?r1w1:(p==2)?r2w1:r3w1;
    const float* W2 = (p==0)?r0w2:(p==1)?r1w2:(p==2)?r2w2:r3w2;
    u16* W1T = g_w1t + p*Dd*Rr;
    u16* W2T = g_w2t + p*Dd*Dd;
    // coalesced reads (linear in), scattered writes (stores don't stall)
    #pragma unroll
    for (int it=0; it<4; it++){
      int in = sl*512 + it*128 + t;                  // in = kk*Dd + dd
      W1T[(in & 127)*Rr + (in >> 7)] = f2bf(W1[in]);
    }
    #pragma unroll
    for (int it=0; it<16; it++){
      int in = sl*2048 + it*128 + t;                 // in = kk*Dd + dd
      W2T[(in & 127)*Dd + (in >> 7)] = f2bf(W2[in]);
    }
  }
}

// ---- main: 8 waves/block, 512 thr, (512,4). Wave w owns d-cols [w*16,+16),
// all j. Pipelined: each barrier region = {GEMM1(t+1)->buf^1 ; GEMM2(t)<-buf}.
// Static LDS addressing inside the body (base+immediate), odd row stride 130
// (bank-spread, no swizzle), zero-row mask. r13 PAIR-LOOP (best verified:
// 63.3 us, VGPR 56, no spill): p-body = runtime u in {0,1} loop (unroll 1),
// each iteration = 2 chunks with static buffer roles. The fully-unrolled
// p-body spilled ~16MB scratch at the (512,4) 128-reg budget; the pair scope
// keeps static addressing AND clean allocation. r16 adds T5 s_setprio(1)
// around GEMM2's MFMA chain: the barrier region has role-diverse waves
// (GEMM1 SiLU-VALU vs GEMM2 MFMA) = the regime where setprio measured +21-39%.
__global__ __launch_bounds__(512,4) void se3_mfma20(
    const float* __restrict__ node_v,
    const float* __restrict__ rbf,
    const float* __restrict__ r_hat,
    const float* __restrict__ maskp,
    const float* __restrict__ r0b1, const float* __restrict__ r0b2,
    const float* __restrict__ r1b1, const float* __restrict__ r1b2,
    const float* __restrict__ r2b1, const float* __restrict__ r2b2,
    const float* __restrict__ r3b1, const float* __restrict__ r3b2,
    const float* __restrict__ ln_g, const float* __restrict__ ln_b,
    const float* __restrict__ out_w, const float* __restrict__ out_b,
    const float* __restrict__ v_scale, const float* __restrict__ t_scale,
    const float* __restrict__ h_ws,
    float* __restrict__ out_s, float* __restrict__ out_v, float* __restrict__ out_t)
{
  __shared__ u16   s_rbf[Nn*40];       // 20480: rbf bf16, row stride 40
  __shared__ u16   s_hid[2*64*130];    // 33280: dbuf, row stride 130 (odd dwords)
  __shared__ u16   s_YT[11*264];       //  5808: rows 0..9 = Y*mask, row 10 = zeros
  __shared__ u16   s_Y1r[3*264];       //  1584
  __shared__ float s_msg[Dd];          //   512
  __shared__ float s_xn[Dd];           //   512
  __shared__ float s_part[4*Dd];       //  2048
  __shared__ float s_mv[2];            //     8  -> total 64232 B (2 blocks/CU)

  const int tid  = threadIdx.x;
  const int bi   = blockIdx.x;            // b*N + i
  const int b    = bi >> 8;
  const int lane = tid & 63;
  const int w    = tid >> 6;              // wave 0..7
  const int q    = lane >> 4;
  const int cc   = lane & 15;
  const int hi5  = cc >> 2, lo2 = cc & 3;
  const int dwb  = w*16;                  // this wave's 16-col d-base

  // ---- setup: stacked-Y rows (mask folded), raw Y1, zero row ----
  if (tid < Nn){
    int j = tid;
    size_t pidx = (size_t)bi*Nn + j;
    float mk = maskp[pidx];
    float x = r_hat[pidx*3+0];
    float y = r_hat[pidx*3+1];
    float z = r_hat[pidx*3+2];
    const float SQ3=1.7320508075688772f;
    const float C15=3.8729833462074170f;
    const float C5H=1.1180339887498949f;
    float y1a=SQ3*x, y1b=SQ3*y, y1c=SQ3*z;
    s_YT[0*264+j]=f2bf(mk);
    s_YT[1*264+j]=f2bf(y1a*mk);
    s_YT[2*264+j]=f2bf(y1b*mk);
    s_YT[3*264+j]=f2bf(y1c*mk);
    s_YT[4*264+j]=f2bf(C15*x*y*mk);
    s_YT[5*264+j]=f2bf(C15*y*z*mk);
    s_YT[6*264+j]=f2bf(C5H*(3.f*z*z-1.f)*mk);
    s_YT[7*264+j]=f2bf(C15*x*z*mk);
    s_YT[8*264+j]=f2bf(0.5f*C15*(x*x-y*y)*mk);
    s_YT[9*264+j]=f2bf(mk);
    s_YT[10*264+j]=0;                     // zero row for masked-off lanes
    s_Y1r[0*264+j]=f2bf(y1a);
    s_Y1r[1*264+j]=f2bf(y1b);
    s_Y1r[2*264+j]=f2bf(y1c);
  }

  const float* rbf_blk = rbf + (size_t)bi*Nn*Rr;
  const float* htb     = h_ws + (size_t)b*Dd*Nn;   // h_T[b][d][i]

  // ---- stage rbf as bf16 (row stride 40): packed pairs ----
  for (int idx=tid; idx<Nn*Rr/2; idx+=512){
    int j = idx >> 4, r2 = (idx & 15)*2;
    const float* src = &rbf_blk[j*Rr + r2];
    float v0 = src[0], v1 = src[1];
    *(u32*)&s_rbf[j*40 + r2] = cvtpk(v0, v1);
  }

  // ---- node_v B-fragment for the dot MFMA (wave's 16 d-cols) ----
  bf16x8 vBf;
  {
    const float* nv = node_v + (size_t)bi*3*Dd;
    int dd = dwb+cc;
    bf16x8 t = {0,0,0,0,0,0,0,0};
    if (q==0){
      t[0]=f2bfs(nv[0*Dd+dd]);
      t[1]=f2bfs(nv[1*Dd+dd]);
      t[2]=f2bfs(nv[2*Dd+dd]);
    }
    vBf=t;
  }

  // ---- per-lane LDS u16-index bases (accesses = base + small runtime chunk
  //      base + compile-time immediate) ----
  const int rbf_base = cc*40 + q*8;                 // + ch*2560 + jt*640
  const int hw_base  = cc*130 + w*16 + q*4;         // + buf*8320 + jt*2080
  const int af_base  = (hi5*8+lo2)*130 + q*8;       // + buf*8320 + g*4160 + mm*520 + ks*32

  __syncthreads();                       // setup + staging visible

  const f32x4 zf = {0.f,0.f,0.f,0.f};
  f32x4 accred = zf;

  // pipeline registers
  bf16x8 w1f;  f32x4 b1v4;               // GEMM1 weights of the pending chunk's p
  bf16x8 w2f[4]; float b2v;
  const u16* ytq;                        // per-p Y row base (+q*8 folded)

  // rb = u16-index base of the chunk in s_rbf (= ch*2560); bufn in {0,1}
  auto do_gemm1 = [&](int rb, int bufn){
    #pragma unroll
    for (int jt=0;jt<4;jt++){
      bf16x8 rbff = *(const bf16x8*)&s_rbf[rbf_base + rb + jt*640];
      f32x4 hc = __builtin_amdgcn_mfma_f32_16x16x32_bf16(w1f, rbff, zf, 0,0,0);
      float s0,s1,s2,s3;
      {
        float x0=hc[0]+b1v4[0], x1=hc[1]+b1v4[1], x2=hc[2]+b1v4[2], x3=hc[3]+b1v4[3];
        s0 = x0*__builtin_amdgcn_rcpf(1.f+__expf(-x0));
        s1 = x1*__builtin_amdgcn_rcpf(1.f+__expf(-x1));
        s2 = x2*__builtin_amdgcn_rcpf(1.f+__expf(-x2));
        s3 = x3*__builtin_amdgcn_rcpf(1.f+__expf(-x3));
      }
      u32x2 pk = { cvtpk(s0, s1), cvtpk(s2, s3) };
      *(u32x2*)&s_hid[bufn*8320 + hw_base + jt*2080] = pk;
    }
  };

  // choff = ch*64 (j units); bufx in {0,1}
  auto do_gemm2 = [&](int choff, int bufx, int p){
    f32x4 hql[2][2];
    if (p<3){
      #pragma unroll
      for (int g=0;g<2;g++)
        #pragma unroll
        for (int mm=0;mm<2;mm++)
          hql[g][mm] = *(const f32x4*)&htb[(size_t)(dwb+cc)*Nn + choff + g*32 + q*8 + mm*4];
    }
    #pragma unroll
    for (int g=0; g<2; g++){
      u32 bB[4];
      #pragma unroll
      for (int mm=0;mm<2;mm++){
        bf16x8 af[4];
        #pragma unroll
        for (int ks=0;ks<4;ks++)
          af[ks] = *(const bf16x8*)&s_hid[bufx*8320 + af_base + g*4160 + mm*520 + ks*32];

        f32x4 dotC;
        if (p==3){                       // dot(v, Y1): A rows follow the tile perm
          bf16x8 aY = {0,0,0,0,0,0,0,0};
          if (q==0){
            int jg = choff + g*32 + hi5*8 + mm*4 + lo2;
            aY[0]=(short)s_Y1r[0*264+jg];
            aY[1]=(short)s_Y1r[1*264+jg];
            aY[2]=(short)s_Y1r[2*264+jg];
          }
          dotC = __builtin_amdgcn_mfma_f32_16x16x32_bf16(aY, vBf, zf, 0,0,0);
        }

        // T5: favor the MFMA-chain wave on the CU scheduler while sibling
        // waves are in GEMM1's SiLU-VALU phase (role-diverse barrier region)
        __builtin_amdgcn_s_setprio(1);
        f32x4 c2 = zf;
        #pragma unroll
        for (int ks=0;ks<4;ks++)
          c2 = __builtin_amdgcn_mfma_f32_16x16x32_bf16(af[ks], w2f[ks], c2, 0,0,0);
        __builtin_amdgcn_s_setprio(0);
        float g0,g1,g2,g3;
        if (p<3){
          g0=(c2[0]+b2v)*hql[g][mm][0]; g1=(c2[1]+b2v)*hql[g][mm][1];
          g2=(c2[2]+b2v)*hql[g][mm][2]; g3=(c2[3]+b2v)*hql[g][mm][3];
        } else {
          g0=(c2[0]+b2v)*dotC[0]; g1=(c2[1]+b2v)*dotC[1];
          g2=(c2[2]+b2v)*dotC[2]; g3=(c2[3]+b2v)*dotC[3];
        }
        bB[mm*2+0] = cvtpk(g0, g1);
        bB[mm*2+1] = cvtpk(g2, g3);
      }
      // j-reduction MFMA over this 32-j group (B-frag from registers)
      bf16x8 aR = *(const bf16x8*)(ytq + choff + g*32);
      u32x4 bw = { bB[0], bB[1], bB[2], bB[3] };
      bf16x8 bG = __builtin_bit_cast(bf16x8, bw);
      accred = __builtin_amdgcn_mfma_f32_16x16x32_bf16(aR, bG, accred, 0,0,0);
    }
  };

  // prologue: p0 GEMM1 weights + chunk 0 -> buf0
  w1f  = *(const bf16x8*)&g_w1t[(dwb+cc)*Rr + q*8];
  b1v4 = *(const f32x4*)&r0b1[dwb + q*4];
  do_gemm1(0, 0);

  #pragma unroll 1
  for (int p=0;p<4;p++){
    // per-p GEMM2-side state (global reads: before barrier, latency overlaps)
    {
      const u16* W2T = g_w2t + p*Dd*Dd;
      #pragma unroll
      for (int ks=0;ks<4;ks++)
        w2f[ks] = *(const bf16x8*)&W2T[(dwb+cc)*Dd + ks*32 + q*8];
      const float* B2p = (p==0)?r0b2:(p==1)?r1b2:(p==2)?r2b2:r3b2;
      b2v = B2p[dwb + cc];
      const int lo = (p==0)?0:(p==1)?1:(p==2)?4:9;
      const int hi = (p==0)?0:(p==1)?3:(p==2)?8:9;
      ytq = &s_YT[((cc>=lo && cc<=hi)?cc:10)*264] + q*8;
    }
    // pair loop: u=0 handles chunks {0,1} (+prefetch ch2),
    //            u=1 handles chunks {2,3} (+prefetch next-p ch0)
    #pragma unroll 1
    for (int u=0; u<2; u++){
      const int rb0   = u*5120;          // s_rbf base of chunk 2u
      const int choff = u*128;           // j-offset of chunk 2u
      __syncthreads();
      do_gemm1(rb0 + 2560, 1);           // ch 2u+1 -> buf1
      do_gemm2(choff, 0, p);             // ch 2u   <- buf0
      __syncthreads();
      if (u==0){
        do_gemm1(rb0 + 5120, 0);         // ch 2 -> buf0
      } else if (p<3){
        w1f  = *(const bf16x8*)&g_w1t[(p+1)*Dd*Rr + (dwb+cc)*Rr + q*8];
        const float* B1n = (p==0)?r1b1:(p==1)?r2b1:r3b1;
        b1v4 = *(const f32x4*)&B1n[dwb + q*4];
        do_gemm1(0, 0);                  // next-p ch0 -> buf0
      }
      do_gemm2(choff + 64, 1, p);        // ch 2u+1 <- buf1
    }
  }

  // ---- scatter accred rows -> outputs / LN inputs (complete per wave) ----
  {
    const int d = dwb + cc;
    #pragma unroll
    for (int r=0;r<4;r++){
      const int rw = q*4 + r;
      float val = accred[r];
      if (rw==0)      s_msg[d] = val;
      else if (rw<=3) out_v[(size_t)bi*3*Dd + (size_t)(rw-1)*Dd + d] = val*v_scale[d];
      else if (rw<=8) out_t[(size_t)bi*5*Dd + (size_t)(rw-4)*Dd + d] = val*t_scale[d];
      else if (rw==9) s_xn[d] = val;
    }
  }
  __syncthreads();

  // ---- LayerNorm stats (wave 0) ----
  if (tid < 64){
    float a0=s_msg[tid]+s_xn[tid], a1=s_msg[tid+64]+s_xn[tid+64];
    float s1=a0+a1, s2=a0*a0+a1*a1;
    #pragma unroll
    for (int off=1;off<64;off<<=1){
      s1 += __shfl_xor(s1,off);
      s2 += __shfl_xor(s2,off);
    }
    if (tid==0){
      float m   = s1*(1.f/Dd);
      float var = fmaxf(s2*(1.f/Dd) - m*m, 0.f);
      s_mv[0]=m;
      s_mv[1]=rsqrtf(var+1e-5f);
    }
  }
  __syncthreads();
  if (tid < Dd){
    float msg = s_msg[tid]+s_xn[tid];
    s_xn[tid] = (msg - s_mv[0])*s_mv[1]*ln_g[tid] + ln_b[tid];
  }
  __syncthreads();

  // ---- delta_s = xn @ out_w + out_b (4 k-segments across 512 threads) ----
  {
    int dp = tid & 127, seg = tid >> 7;
    float pa = 0.f;
    #pragma unroll 8
    for (int k=seg*32;k<seg*32+32;k++)
      pa += s_xn[k]*out_w[k*Dd+dp];
    s_part[seg*Dd+dp]=pa;
  }
  __syncthreads();
  if (tid < Dd)
    out_s[(size_t)bi*Dd+tid] = s_part[tid]+s_part[Dd+tid]+s_part[2*Dd+tid]+s_part[3*Dd+tid]+out_b[tid];
}

extern "C" void kernel_launch(void* const* d_in, const int* in_sizes, int n_in,
                              void* d_out, int out_size, void* d_ws, size_t ws_size,
                              hipStream_t stream) {
  const float* node_s = (const float*)d_in[0];
  const float* node_v = (const float*)d_in[1];
  // d_in[2] = node_t (unused by reference)
  const float* rbf    = (const float*)d_in[3];
  const float* r_hat  = (const float*)d_in[4];
  const float* maskp  = (const float*)d_in[5];
  const float* r0w1=(const float*)d_in[6],  *r0b1=(const float*)d_in[7];
  const float* r0w2=(const float*)d_in[8],  *r0b2=(const float*)d_in[9];
  const float* r1w1=(const float*)d_in[10], *r1b1=(const float*)d_in[11];
  const float* r1w2=(const float*)d_in[12], *r1b2=(const float*)d_in[13];
  const float* r2w1=(const float*)d_in[14], *r2b1=(const float*)d_in[15];
  const float* r2w2=(const float*)d_in[16], *r2b2=(const float*)d_in[17];
  const float* r3w1=(const float*)d_in[18], *r3b1=(const float*)d_in[19];
  const float* r3w2=(const float*)d_in[20], *r3b2=(const float*)d_in[21];
  const float* src_w  =(const float*)d_in[22];
  const float* ln_g   =(const float*)d_in[23];
  const float* ln_b   =(const float*)d_in[24];
  const float* out_w  =(const float*)d_in[25];
  const float* out_b  =(const float*)d_in[26];
  const float* v_scale=(const float*)d_in[27];
  const float* t_scale=(const float*)d_in[28];

  float* h_ws = (float*)d_ws;                    // h_T: 2*128*256 f32 = 256 KiB
  float* out_s = (float*)d_out;
  float* out_v = out_s + (size_t)Bb*Nn*Dd;
  float* out_t = out_v + (size_t)Bb*Nn*3*Dd;

  prep_kernel<<<dim3(Bb*Nn + 32), dim3(128), 0, stream>>>(
      node_s, src_w,
      r0w1, r1w1, r2w1, r3w1, r0w2, r1w2, r2w2, r3w2,
      h_ws);
  se3_mfma20<<<dim3(Bb*Nn), dim3(512), 0, stream>>>(
      node_v, rbf, r_hat, maskp,
      r0b1,r0b2, r1b1,r1b2, r2b1,r2b2, r3b1,r3b2,
      ln_g, ln_b, out_w, out_b, v_scale, t_scale,
      h_ws, out_s, out_v, out_t);
}